// Round 1
// baseline (322.391 us; speedup 1.0000x reference)
//
#include <hip/hip_runtime.h>
#include <hip/hip_bf16.h>

#define EPSQ 1e-5f

typedef __hip_bfloat16 bf16;
using short8 = __attribute__((ext_vector_type(8))) short;   // 8 bf16 = 4 VGPRs
using f32x4  = __attribute__((ext_vector_type(4))) float;

constexpr int DIM = 4096;           // M = N = K = 4096
constexpr int BM = 128, BN = 128, BK = 64;

// ---------------------------------------------------------------------------
// async global->LDS, 16 B per lane. LDS dest = wave-uniform base + lane*16.
// ---------------------------------------------------------------------------
__device__ __forceinline__ void gload_lds16(const bf16* g, bf16* l) {
  __builtin_amdgcn_global_load_lds(
      (const __attribute__((address_space(1))) void*)(g),
      (__attribute__((address_space(3))) void*)(l), 16, 0, 0);
}

__device__ __forceinline__ unsigned short f2bf(float f) {
  __hip_bfloat16 h = __float2bfloat16(f);   // RNE
  unsigned short u;
  __builtin_memcpy(&u, &h, 2);
  return u;
}

// ---------------------------------------------------------------------------
// sum(|T|) reduction, T = (V - Vp*cos)/sin.  Only runs when bias != 0.
// ---------------------------------------------------------------------------
__global__ void k_absmean(const float* __restrict__ V, const float* __restrict__ Vp,
                          const float* __restrict__ theta_p, const float* __restrict__ bias_p,
                          float* __restrict__ sum_out, int total) {
  if (bias_p[0] == 0.0f) return;
  float ct = cosf(theta_p[0]);
  float st = sinf(theta_p[0]);
  float acc = 0.0f;
  int stride = gridDim.x * blockDim.x;
  for (int i = blockIdx.x * blockDim.x + threadIdx.x; i < total; i += stride) {
    float t = (V[i] - Vp[i] * ct) / st;
    acc += fabsf(t);
  }
  #pragma unroll
  for (int off = 32; off > 0; off >>= 1) acc += __shfl_down(acc, off, 64);
  __shared__ float wsum[4];
  int lane = threadIdx.x & 63, w = threadIdx.x >> 6;
  if (lane == 0) wsum[w] = acc;
  __syncthreads();
  if (threadIdx.x == 0) {
    atomicAdd(sum_out, wsum[0] + wsum[1] + wsum[2] + wsum[3]);
  }
}

// ---------------------------------------------------------------------------
// Convert X->bf16 (Xb), Vp->bf16 (W1); if bias!=0 also ternarize T into W2.
// ---------------------------------------------------------------------------
__global__ void k_convert(const float4* __restrict__ X4, const float4* __restrict__ V4,
                          const float4* __restrict__ Vp4,
                          const float* __restrict__ theta_p, const float* __restrict__ bias_p,
                          const float* __restrict__ sum_p,
                          ushort4* __restrict__ Xb, ushort4* __restrict__ W1,
                          ushort4* __restrict__ W2, int total4) {
  bool doT = (bias_p[0] != 0.0f);
  float ct = cosf(theta_p[0]);
  float st = sinf(theta_p[0]);
  float scale = 0.0f;
  if (doT) {
    float mean = sum_p[0] / 16777216.0f;          // O*I = 4096*4096
    mean = fmaxf(mean, EPSQ);                     // clip(mean, EPS, None)
    scale = 1.0f / mean;
  }
  int stride = gridDim.x * blockDim.x;
  for (int i = blockIdx.x * blockDim.x + threadIdx.x; i < total4; i += stride) {
    float4 x  = X4[i];
    float4 vp = Vp4[i];
    ushort4 ux, uw;
    ux.x = f2bf(x.x);  ux.y = f2bf(x.y);  ux.z = f2bf(x.z);  ux.w = f2bf(x.w);
    uw.x = f2bf(vp.x); uw.y = f2bf(vp.y); uw.z = f2bf(vp.z); uw.w = f2bf(vp.w);
    Xb[i] = ux;
    W1[i] = uw;
    if (doT) {
      float4 v = V4[i];
      float t0 = (v.x - vp.x * ct) / st;
      float t1 = (v.y - vp.y * ct) / st;
      float t2 = (v.z - vp.z * ct) / st;
      float t3 = (v.w - vp.w * ct) / st;
      // round half-to-even then clamp to {-1,0,1}
      float q0 = fminf(fmaxf(rintf(t0 * scale), -1.0f), 1.0f);
      float q1 = fminf(fmaxf(rintf(t1 * scale), -1.0f), 1.0f);
      float q2 = fminf(fmaxf(rintf(t2 * scale), -1.0f), 1.0f);
      float q3 = fminf(fmaxf(rintf(t3 * scale), -1.0f), 1.0f);
      ushort4 uq;
      uq.x = f2bf(q0); uq.y = f2bf(q1); uq.z = f2bf(q2); uq.w = f2bf(q3);
      W2[i] = uq;
    }
  }
}

// ---------------------------------------------------------------------------
// bf16 MFMA GEMM, m97 structure: 128x128 tile, BK=64, 4 waves (2x2 of 64x64),
// 16x16x32 MFMA, global_load_lds width 16, XOR-swizzled LDS chunk layout.
// A = Xb [M,K] row-major; B = W [N,K] row-major (i.e. B^T-input GEMM).
//   which == 0 : C = sign(X@W2.T) * bias        (skipped entirely if bias==0)
//   which == 1 : C = cos(theta)*(X@W1.T) [+ C if bias != 0]
// ---------------------------------------------------------------------------
__global__ __launch_bounds__(256, 3)
void k_gemm(const bf16* __restrict__ A, const bf16* __restrict__ B,
            float* __restrict__ C,
            const float* __restrict__ theta_p, const float* __restrict__ bias_p,
            int which) {
  float biasv = bias_p[0];
  if (which == 0 && biasv == 0.0f) return;

  __shared__ bf16 As[BM * BK];   // 16 KiB, chunk-swizzled: row r chunk c at r*8 + (c^(r&7))
  __shared__ bf16 Bs[BN * BK];   // 16 KiB

  const int tid  = threadIdx.x;
  const int lane = tid & 63;
  const int w    = tid >> 6;
  const int bm   = blockIdx.y * BM;
  const int bn   = blockIdx.x * BN;
  const int wm   = (w >> 1) * 64;
  const int wn   = (w & 1) * 64;
  const int q    = lane >> 4;         // k-quad 0..3
  const int l15  = lane & 15;

  f32x4 acc[4][4] = {};

  for (int kt = 0; kt < DIM; kt += BK) {
    __syncthreads();                  // all waves done reading previous tile
    #pragma unroll
    for (int j = 0; j < 4; ++j) {
      int ia = w * 4 + j;             // wave-issue id, covers LDS chunks [ia*64, ia*64+64)
      int p  = ia * 64 + lane;        // this lane's LDS chunk position
      int r  = p >> 3;                // tile row
      int c  = (p & 7) ^ (r & 7);     // source k-chunk (XOR swizzle)
      gload_lds16(A + (size_t)(bm + r) * DIM + kt + c * 8, &As[ia * 512]);
      gload_lds16(B + (size_t)(bn + r) * DIM + kt + c * 8, &Bs[ia * 512]);
    }
    __syncthreads();                  // vmcnt(0) drain: tiles ready
    #pragma unroll
    for (int s = 0; s < 2; ++s) {
      short8 af[4], bfr[4];
      #pragma unroll
      for (int i = 0; i < 4; ++i) {
        int m    = wm + i * 16 + l15;
        int ca   = (s * 4 + q) ^ (m & 7);
        af[i]    = *(const short8*)&As[(m * 8 + ca) * 8];
        int n    = wn + i * 16 + l15;
        int cb   = (s * 4 + q) ^ (n & 7);
        bfr[i]   = *(const short8*)&Bs[(n * 8 + cb) * 8];
      }
      #pragma unroll
      for (int i = 0; i < 4; ++i)
        #pragma unroll
        for (int j = 0; j < 4; ++j)
          acc[i][j] = __builtin_amdgcn_mfma_f32_16x16x32_bf16(af[i], bfr[j], acc[i][j], 0, 0, 0);
    }
  }

  // Epilogue. C/D layout: row(M) = q*4 + reg, col(N) = lane&15 (per 16x16 tile).
  float ct = cosf(theta_p[0]);
  #pragma unroll
  for (int i = 0; i < 4; ++i) {
    int mbase = bm + wm + i * 16 + q * 4;
    #pragma unroll
    for (int j = 0; j < 4; ++j) {
      int n = bn + wn + j * 16 + l15;
      #pragma unroll
      for (int r = 0; r < 4; ++r) {
        size_t idx = (size_t)(mbase + r) * DIM + n;
        float v = acc[i][j][r];
        if (which == 0) {
          float s = (v > 0.0f) ? 1.0f : ((v < 0.0f) ? -1.0f : 0.0f);
          C[idx] = s * biasv;                       // sign(X_T*100)*bias
        } else {
          float outv = ct * v;
          if (biasv != 0.0f) outv += C[idx];        // add sign-term from pass 0
          C[idx] = outv;
        }
      }
    }
  }
}

// ---------------------------------------------------------------------------
extern "C" void kernel_launch(void* const* d_in, const int* in_sizes, int n_in,
                              void* d_out, int out_size, void* d_ws, size_t ws_size,
                              hipStream_t stream) {
  const float* V     = (const float*)d_in[0];
  const float* Vp    = (const float*)d_in[1];
  const float* X     = (const float*)d_in[2];
  const float* theta = (const float*)d_in[3];
  const float* bias  = (const float*)d_in[4];
  float* out = (float*)d_out;

  const size_t SZ = (size_t)DIM * DIM;   // 16,777,216 elements
  char* ws = (char*)d_ws;
  float* sum_p = (float*)ws;             // |T| sum accumulator
  bf16* Xb = (bf16*)(ws + 256);          // 32 MiB
  bf16* W1 = Xb + SZ;                    // 32 MiB (V_p bf16)
  bf16* W2 = W1 + SZ;                    // 32 MiB (Tq bf16, only if bias!=0)

  hipMemsetAsync(sum_p, 0, 16, stream);
  k_absmean<<<2048, 256, 0, stream>>>(V, Vp, theta, bias, sum_p, (int)SZ);
  k_convert<<<2048, 256, 0, stream>>>((const float4*)X, (const float4*)V,
                                      (const float4*)Vp, theta, bias, sum_p,
                                      (ushort4*)Xb, (ushort4*)W1, (ushort4*)W2,
                                      (int)(SZ / 4));
  dim3 grid(DIM / BN, DIM / BM);         // 32 x 32
  k_gemm<<<grid, 256, 0, stream>>>(Xb, W2, out, theta, bias, 0);
  k_gemm<<<grid, 256, 0, stream>>>(Xb, W1, out, theta, bias, 1);
}

// Round 2
// 264.390 us; speedup vs baseline: 1.2194x; 1.2194x over previous
//
#include <hip/hip_runtime.h>
#include <hip/hip_bf16.h>

#define EPSQ 1e-5f

typedef signed char i8;
using int4v = __attribute__((ext_vector_type(4))) int;

constexpr int DIM = 4096;           // M = N = K = 4096
constexpr int BM = 128, BN = 128, BK = 128;   // BK in i8 elements (= bytes)

// ---------------------------------------------------------------------------
// async global->LDS, 16 B per lane. LDS dest = wave-uniform base + lane*16.
// ---------------------------------------------------------------------------
__device__ __forceinline__ void gload_lds16(const void* g, void* l) {
  __builtin_amdgcn_global_load_lds(
      (const __attribute__((address_space(1))) void*)(g),
      (__attribute__((address_space(3))) void*)(l), 16, 0, 0);
}

// ---------------------------------------------------------------------------
// sum(|T|) reduction, T = (V - Vp*cos)/sin.  Only runs when bias != 0.
// ---------------------------------------------------------------------------
__global__ void k_absmean(const float* __restrict__ V, const float* __restrict__ Vp,
                          const float* __restrict__ theta_p, const float* __restrict__ bias_p,
                          float* __restrict__ sum_out, int total) {
  if (bias_p[0] == 0.0f) return;
  float ct = cosf(theta_p[0]);
  float st = sinf(theta_p[0]);
  float acc = 0.0f;
  int stride = gridDim.x * blockDim.x;
  for (int i = blockIdx.x * blockDim.x + threadIdx.x; i < total; i += stride) {
    float t = (V[i] - Vp[i] * ct) / st;
    acc += fabsf(t);
  }
  #pragma unroll
  for (int off = 32; off > 0; off >>= 1) acc += __shfl_down(acc, off, 64);
  __shared__ float wsum[4];
  int lane = threadIdx.x & 63, w = threadIdx.x >> 6;
  if (lane == 0) wsum[w] = acc;
  __syncthreads();
  if (threadIdx.x == 0) atomicAdd(sum_out, wsum[0] + wsum[1] + wsum[2] + wsum[3]);
}

// ---------------------------------------------------------------------------
// Fused prep:
//   blocks [0, 4096)        : per-row symmetric i8 quant of X, rs[row] = max|x|/127
//   blocks [4096, 4096+2048): Vp -> i8 (exact, ternary); if bias!=0 also Tq -> i8
// ---------------------------------------------------------------------------
__global__ __launch_bounds__(256)
void k_prep(const float* __restrict__ X, const float* __restrict__ V,
            const float* __restrict__ Vp,
            const float* __restrict__ theta_p, const float* __restrict__ bias_p,
            const float* __restrict__ sum_p,
            i8* __restrict__ Xq, float* __restrict__ rs,
            i8* __restrict__ W1, i8* __restrict__ W2) {
  __shared__ float wmx[4];
  const int tid = threadIdx.x;
  if (blockIdx.x < 4096) {
    // ---- X row quantization ----
    const int row = blockIdx.x;
    const float4* Xr = (const float4*)(X + (size_t)row * DIM);
    float4 f[4];
    float mx = 0.0f;
    #pragma unroll
    for (int t = 0; t < 4; ++t) {
      f[t] = Xr[tid + t * 256];
      mx = fmaxf(mx, fmaxf(fmaxf(fabsf(f[t].x), fabsf(f[t].y)),
                           fmaxf(fabsf(f[t].z), fabsf(f[t].w))));
    }
    #pragma unroll
    for (int off = 32; off > 0; off >>= 1) mx = fmaxf(mx, __shfl_down(mx, off, 64));
    int lane = tid & 63, w = tid >> 6;
    if (lane == 0) wmx[w] = mx;
    __syncthreads();
    mx = fmaxf(fmaxf(wmx[0], wmx[1]), fmaxf(wmx[2], wmx[3]));
    mx = fmaxf(mx, 1e-30f);
    float rsv = mx / 127.0f;
    if (tid == 0) rs[row] = rsv;
    float inv = 1.0f / rsv;
    char4* Xo = (char4*)(Xq + (size_t)row * DIM);
    #pragma unroll
    for (int t = 0; t < 4; ++t) {
      char4 qv;
      qv.x = (i8)fminf(fmaxf(rintf(f[t].x * inv), -127.0f), 127.0f);
      qv.y = (i8)fminf(fmaxf(rintf(f[t].y * inv), -127.0f), 127.0f);
      qv.z = (i8)fminf(fmaxf(rintf(f[t].z * inv), -127.0f), 127.0f);
      qv.w = (i8)fminf(fmaxf(rintf(f[t].w * inv), -127.0f), 127.0f);
      Xo[tid + t * 256] = qv;
    }
  } else {
    // ---- weight quantization ----
    bool doT = (bias_p[0] != 0.0f);
    float ct = cosf(theta_p[0]);
    float st = sinf(theta_p[0]);
    float scale = 0.0f;
    if (doT) {
      float mean = sum_p[0] / 16777216.0f;
      mean = fmaxf(mean, EPSQ);
      scale = 1.0f / mean;
    }
    const float4* Vp4 = (const float4*)Vp;
    const float4* V4  = (const float4*)V;
    char4* W1o = (char4*)W1;
    char4* W2o = (char4*)W2;
    const int total4 = DIM * DIM / 4;
    const int stride = 2048 * 256;
    for (int i = (int)(blockIdx.x - 4096) * 256 + tid; i < total4; i += stride) {
      float4 vp = Vp4[i];
      char4 w1;
      w1.x = (i8)vp.x; w1.y = (i8)vp.y; w1.z = (i8)vp.z; w1.w = (i8)vp.w;  // exact ternary
      W1o[i] = w1;
      if (doT) {
        float4 v = V4[i];
        float q0 = fminf(fmaxf(rintf(((v.x - vp.x * ct) / st) * scale), -1.0f), 1.0f);
        float q1 = fminf(fmaxf(rintf(((v.y - vp.y * ct) / st) * scale), -1.0f), 1.0f);
        float q2 = fminf(fmaxf(rintf(((v.z - vp.z * ct) / st) * scale), -1.0f), 1.0f);
        float q3 = fminf(fmaxf(rintf(((v.w - vp.w * ct) / st) * scale), -1.0f), 1.0f);
        char4 w2;
        w2.x = (i8)q0; w2.y = (i8)q1; w2.z = (i8)q2; w2.w = (i8)q3;
        W2o[i] = w2;
      }
    }
  }
}

// ---------------------------------------------------------------------------
// i8 MFMA GEMM: 128x128 tile, BK=128 bytes, 4 waves (2x2 of 64x64),
// mfma_i32_16x16x64_i8, global_load_lds width 16, XOR-swizzled LDS chunks.
// A = Xq [M,K], B = W [N,K] (both row-major i8).
//   which == 0 : C = sign(X@W2.T) * bias        (skipped entirely if bias==0)
//   which == 1 : C = cos(theta)*rs[m]*(X@W1.T) [+ C if bias != 0]
// ---------------------------------------------------------------------------
__global__ __launch_bounds__(256, 3)
void k_gemm(const i8* __restrict__ A, const i8* __restrict__ B,
            float* __restrict__ C, const float* __restrict__ rs,
            const float* __restrict__ theta_p, const float* __restrict__ bias_p,
            int which) {
  float biasv = bias_p[0];
  if (which == 0 && biasv == 0.0f) return;

  __shared__ i8 As[BM * BK];   // 16 KiB, chunk-swizzled: row r, chunk c at r*8 + (c^(r&7))
  __shared__ i8 Bs[BN * BK];   // 16 KiB

  const int tid  = threadIdx.x;
  const int lane = tid & 63;
  const int w    = tid >> 6;
  const int bm   = blockIdx.y * BM;
  const int bn   = blockIdx.x * BN;
  const int wm   = (w >> 1) * 64;
  const int wn   = (w & 1) * 64;
  const int q    = lane >> 4;         // k-quad 0..3
  const int l15  = lane & 15;

  int4v acc[4][4] = {};

  for (int kt = 0; kt < DIM; kt += BK) {
    __syncthreads();                  // all waves done reading previous tile
    #pragma unroll
    for (int j = 0; j < 4; ++j) {
      int ia = w * 4 + j;             // wave-issue id
      int p  = ia * 64 + lane;        // chunk position (16 B chunks, 8 per row)
      int r  = p >> 3;                // tile row
      int c  = (p & 7) ^ (r & 7);     // source k-chunk (XOR swizzle)
      gload_lds16(A + (size_t)(bm + r) * DIM + kt + c * 16, &As[ia * 1024]);
      gload_lds16(B + (size_t)(bn + r) * DIM + kt + c * 16, &Bs[ia * 1024]);
    }
    __syncthreads();                  // tiles ready
    #pragma unroll
    for (int s = 0; s < 2; ++s) {
      int4v af[4], bfr[4];
      #pragma unroll
      for (int i = 0; i < 4; ++i) {
        int m  = wm + i * 16 + l15;
        int ca = (s * 4 + q) ^ (m & 7);
        af[i]  = *(const int4v*)&As[(m * 8 + ca) * 16];
        int n  = wn + i * 16 + l15;
        int cb = (s * 4 + q) ^ (n & 7);
        bfr[i] = *(const int4v*)&Bs[(n * 8 + cb) * 16];
      }
      #pragma unroll
      for (int i = 0; i < 4; ++i)
        #pragma unroll
        for (int j = 0; j < 4; ++j)
          acc[i][j] = __builtin_amdgcn_mfma_i32_16x16x64_i8(af[i], bfr[j], acc[i][j], 0, 0, 0);
    }
  }

  // Epilogue. C/D layout: row(M) = q*4 + reg, col(N) = lane&15 (per 16x16 tile).
  float ct = cosf(theta_p[0]);
  #pragma unroll
  for (int i = 0; i < 4; ++i) {
    int mbase = bm + wm + i * 16 + q * 4;
    float sc[4];
    #pragma unroll
    for (int r = 0; r < 4; ++r) sc[r] = ct * rs[mbase + r];
    #pragma unroll
    for (int j = 0; j < 4; ++j) {
      int n = bn + wn + j * 16 + l15;
      #pragma unroll
      for (int r = 0; r < 4; ++r) {
        size_t idx = (size_t)(mbase + r) * DIM + n;
        int v = acc[i][j][r];
        if (which == 0) {
          float s = (v > 0) ? 1.0f : ((v < 0) ? -1.0f : 0.0f);
          C[idx] = s * biasv;                       // sign(X_T*100)*bias
        } else {
          float outv = sc[r] * (float)v;
          if (biasv != 0.0f) outv += C[idx];        // add sign-term from pass 0
          C[idx] = outv;
        }
      }
    }
  }
}

// ---------------------------------------------------------------------------
extern "C" void kernel_launch(void* const* d_in, const int* in_sizes, int n_in,
                              void* d_out, int out_size, void* d_ws, size_t ws_size,
                              hipStream_t stream) {
  const float* V     = (const float*)d_in[0];
  const float* Vp    = (const float*)d_in[1];
  const float* X     = (const float*)d_in[2];
  const float* theta = (const float*)d_in[3];
  const float* bias  = (const float*)d_in[4];
  float* out = (float*)d_out;

  const size_t SZ = (size_t)DIM * DIM;   // 16,777,216 elements
  char* ws = (char*)d_ws;
  float* sum_p = (float*)ws;             // |T| sum accumulator
  float* rs    = (float*)(ws + 256);     // 16 KiB row scales
  i8* Xq = (i8*)(ws + 256 + 16384);      // 16 MiB
  i8* W1 = Xq + SZ;                      // 16 MiB (V_p i8, exact)
  i8* W2 = W1 + SZ;                      // 16 MiB (Tq i8, only if bias!=0)

  hipMemsetAsync(sum_p, 0, 16, stream);
  k_absmean<<<2048, 256, 0, stream>>>(V, Vp, theta, bias, sum_p, (int)SZ);
  k_prep<<<4096 + 2048, 256, 0, stream>>>(X, V, Vp, theta, bias, sum_p,
                                          Xq, rs, W1, W2);
  dim3 grid(DIM / BN, DIM / BM);         // 32 x 32
  k_gemm<<<grid, 256, 0, stream>>>(Xq, W2, out, rs, theta, bias, 0);
  k_gemm<<<grid, 256, 0, stream>>>(Xq, W1, out, rs, theta, bias, 1);
}